// Round 1
// 960.809 us; speedup vs baseline: 1.2884x; 1.2884x over previous
//
#include <hip/hip_runtime.h>

// ---------------- types ----------------
using short8 = __attribute__((ext_vector_type(8))) short;
using f32x4  = __attribute__((ext_vector_type(4))) float;
using u16x4  = __attribute__((ext_vector_type(4))) unsigned short;

#define SCALE 0.17677669529663687f   // 32^-0.5
#define XS  264                       // x / q / k / o LDS stride (bf16 elems)
#define QS2 264
#define VS  72                        // vT stride
#define PS  72                        // P stride
// LDS (u16 offsets): s_x 0, s_q 16896, s_k 33792, s_vT 50688 (256x72),
// s_p 69120 (8 waves x [16][72]) -> total 78336 u16 = 156672 B
#define LDS_BYTES 156672

__device__ __forceinline__ unsigned short f2bf(float f) {
    union { float f; unsigned u; } v; v.f = f;
    unsigned u = v.u;
    return (unsigned short)((u + 0x7FFFu + ((u >> 16) & 1u)) >> 16);
}

// ---------------- prep: fp32->bf16 weights + rel-bias table ----------------
__global__ void prep_kernel(const float* __restrict__ wqkv, const float* __restrict__ wout,
                            const float* __restrict__ relpos,
                            unsigned short* __restrict__ wqkv_bf,
                            unsigned short* __restrict__ wout_bf,
                            float* __restrict__ relT) {
    int i = blockIdx.x * 256 + threadIdx.x;
    if (i < 768 * 256) wqkv_bf[i] = f2bf(wqkv[i]);
    if (i < 256 * 256) wout_bf[i] = f2bf(wout[i]);
    if (i < 8 * 64 * 64) {
        int h = i >> 12, p = (i >> 6) & 63, q = i & 63;
        int r0 = (p >> 3) - (q >> 3) + 7;
        int r1 = (p & 7) - (q & 7) + 7;
        relT[i] = relpos[(h * 15 + r0) * 15 + r1];
    }
}

// ---------------- fused W-MSA: one block per (batch, window), 8 waves ----------------
// Wave w owns head w: it computes q/k/v columns [32w,32w+32) in the QKV GEMM,
// so all attention inputs are wave-private (no barrier between GEMM and attention).
__global__ __launch_bounds__(512, 2) void wmsa_kernel(
    const float* __restrict__ x,
    const unsigned short* __restrict__ wqkv_bf,
    const float* __restrict__ bqkv,
    const float* __restrict__ relT,
    const unsigned short* __restrict__ wout_bf,
    const float* __restrict__ bout,
    float* __restrict__ out) {

    extern __shared__ unsigned short lds[];
    unsigned short* s_x  = lds;            // [64][264], dead after QKV GEMM
    unsigned short* s_q  = lds + 16896;    // [64][264] scaled q; O overwrites in place
    unsigned short* s_k  = lds + 33792;    // [64][264]
    unsigned short* s_vT = lds + 50688;    // [256][72]  V transposed: [chan][token]
    unsigned short* s_p  = lds + 69120;    // 8 x [16][72] streaming P per wave

    const int blk  = blockIdx.x;
    const int bi   = blk >> 10;
    const int w    = blk & 1023;
    const int wy   = w >> 5, wx = w & 31;
    const int tid  = threadIdx.x;
    const int wid  = tid >> 6;            // wave id == head id
    const int lane = tid & 63;
    const int quad = lane >> 4;
    const int l16  = lane & 15;

    // Reference quirk: out.transpose(1,0,2,3,4).reshape scrambles (window,batch);
    // attention uses the ORIGINAL window, only the store location is scrambled.
    const int e   = ((wy * 32 + wx) << 2) + bi;
    const int bo  = e >> 10;
    const int wyo = (e >> 5) & 31;
    const int wxo = e & 31;

    // ---- stage x window -> LDS bf16 (roll folded into source index) ----
    {
        int tok = tid >> 3, qd = tid & 7;
        int ty = tok >> 3, tx = tok & 7;
        int ysrc = (wy * 8 + ty + 4) & 255;
        int xsrc = (wx * 8 + tx + 4) & 255;
        const float* src = x + (((size_t)bi * 256 + ysrc) * 256 + xsrc) * 256;
        unsigned short* dst = s_x + tok * XS;
        #pragma unroll
        for (int j = 0; j < 8; ++j) {
            int ch = j * 32 + qd * 4;
            float4 v4 = *(const float4*)(src + ch);
            u16x4 pk = { f2bf(v4.x), f2bf(v4.y), f2bf(v4.z), f2bf(v4.w) };
            *(u16x4*)(dst + ch) = pk;
        }
    }
    __syncthreads();

    // ---- QKV GEMM: wave w computes its head's 96 columns (q,k,v x 32) ----
    {
        short8 afr[4][8];
        #pragma unroll
        for (int mt = 0; mt < 4; ++mt)
            #pragma unroll
            for (int k = 0; k < 8; ++k)
                afr[mt][k] = *(const short8*)(s_x + (mt * 16 + l16) * XS + k * 32 + quad * 8);

        #pragma unroll
        for (int nt = 0; nt < 6; ++nt) {
            const int sec = nt >> 1;                         // 0=q 1=k 2=v
            const int N0  = sec * 256 + wid * 32 + (nt & 1) * 16;
            short8 bfr[8];
            const unsigned short* brow = wqkv_bf + (N0 + l16) * 256 + quad * 8;
            #pragma unroll
            for (int k = 0; k < 8; ++k) bfr[k] = *(const short8*)(brow + k * 32);

            f32x4 z = {0.f, 0.f, 0.f, 0.f};
            f32x4 acc[4] = {z, z, z, z};
            #pragma unroll
            for (int k = 0; k < 8; ++k)
                #pragma unroll
                for (int mt = 0; mt < 4; ++mt)
                    acc[mt] = __builtin_amdgcn_mfma_f32_16x16x32_bf16(afr[mt][k], bfr[k], acc[mt], 0, 0, 0);

            const float bias = bqkv[N0 + l16];
            const int   col  = wid * 32 + (nt & 1) * 16 + l16;
            if (sec == 0) {
                #pragma unroll
                for (int mt = 0; mt < 4; ++mt)
                    #pragma unroll
                    for (int r = 0; r < 4; ++r)
                        s_q[(mt * 16 + quad * 4 + r) * QS2 + col] = f2bf((acc[mt][r] + bias) * SCALE);
            } else if (sec == 1) {
                #pragma unroll
                for (int mt = 0; mt < 4; ++mt)
                    #pragma unroll
                    for (int r = 0; r < 4; ++r)
                        s_k[(mt * 16 + quad * 4 + r) * QS2 + col] = f2bf(acc[mt][r] + bias);
            } else {
                // V transposed: rows (quad*4+r) become 4 consecutive u16 -> packed 8B write
                #pragma unroll
                for (int mt = 0; mt < 4; ++mt) {
                    u16x4 pk = { f2bf(acc[mt][0] + bias), f2bf(acc[mt][1] + bias),
                                 f2bf(acc[mt][2] + bias), f2bf(acc[mt][3] + bias) };
                    *(u16x4*)(s_vT + col * VS + mt * 16 + quad * 4) = pk;
                }
            }
        }
    }
    // NO barrier: q/k/vT columns of head wid were written by this wave only.
    // Compiler inserts lgkmcnt for the aliasing LDS RAW (same-wave, cross-lane).

    // ---- attention: head h = wid ----
    {
        const int h = wid;
        const float* relh = relT + h * 4096;
        const bool mrow = (wy == 31), mcol = (wx == 31);

        short8 qf[4], kf[4];
        #pragma unroll
        for (int i = 0; i < 4; ++i) {
            qf[i] = *(const short8*)(s_q + (i * 16 + l16) * QS2 + h * 32 + quad * 8);
            kf[i] = *(const short8*)(s_k + (i * 16 + l16) * QS2 + h * 32 + quad * 8);
        }

        f32x4 st[4][4];
        #pragma unroll
        for (int mt = 0; mt < 4; ++mt)
            #pragma unroll
            for (int nt = 0; nt < 4; ++nt) {
                f32x4 z = {0.f, 0.f, 0.f, 0.f};
                st[mt][nt] = __builtin_amdgcn_mfma_f32_16x16x32_bf16(qf[mt], kf[nt], z, 0, 0, 0);
            }

        // V fragments: 4 vector reads (vs 32 scalar gathers before)
        short8 vfr[2][2];
        #pragma unroll
        for (int n2 = 0; n2 < 2; ++n2)
            #pragma unroll
            for (int k2 = 0; k2 < 2; ++k2)
                vfr[n2][k2] = *(const short8*)(s_vT + (h * 32 + n2 * 16 + l16) * VS + k2 * 32 + quad * 8);

        unsigned short* pw = s_p + wid * 16 * PS;

        #pragma unroll
        for (int mt = 0; mt < 4; ++mt) {
            // softmax rows mt*16 .. mt*16+15 -> streaming P block
            #pragma unroll
            for (int r = 0; r < 4; ++r) {
                const int p = mt * 16 + quad * 4 + r;
                const int ty = p >> 3, tx = p & 7;
                float vals[4];
                #pragma unroll
                for (int nt = 0; nt < 4; ++nt) {
                    const int qq = nt * 16 + l16;
                    const int qy = qq >> 3, qx = qq & 7;
                    const bool msk = (mrow && ((ty < 4) != (qy < 4))) || (mcol && ((tx < 4) != (qx < 4)));
                    vals[nt] = msk ? -1e30f : (st[mt][nt][r] + relh[p * 64 + qq]);
                }
                float mx = fmaxf(fmaxf(vals[0], vals[1]), fmaxf(vals[2], vals[3]));
                #pragma unroll
                for (int off = 1; off < 16; off <<= 1) mx = fmaxf(mx, __shfl_xor(mx, off, 16));
                float s = 0.f;
                #pragma unroll
                for (int nt = 0; nt < 4; ++nt) { vals[nt] = __expf(vals[nt] - mx); s += vals[nt]; }
                #pragma unroll
                for (int off = 1; off < 16; off <<= 1) s += __shfl_xor(s, off, 16);
                const float inv = 1.0f / s;
                unsigned short* prow = pw + (quad * 4 + r) * PS;
                #pragma unroll
                for (int nt = 0; nt < 4; ++nt) prow[nt * 16 + l16] = f2bf(vals[nt] * inv);
            }

            // PV for this 16-row block; O overwrites dead q columns in place
            f32x4 z = {0.f, 0.f, 0.f, 0.f};
            f32x4 oacc[2] = {z, z};
            #pragma unroll
            for (int k2 = 0; k2 < 2; ++k2) {
                short8 pf = *(const short8*)(pw + l16 * PS + k2 * 32 + quad * 8);
                #pragma unroll
                for (int n2 = 0; n2 < 2; ++n2)
                    oacc[n2] = __builtin_amdgcn_mfma_f32_16x16x32_bf16(pf, vfr[n2][k2], oacc[n2], 0, 0, 0);
            }
            #pragma unroll
            for (int n2 = 0; n2 < 2; ++n2)
                #pragma unroll
                for (int r = 0; r < 4; ++r)
                    s_q[(mt * 16 + quad * 4 + r) * QS2 + h * 32 + n2 * 16 + l16] = f2bf(oacc[n2][r]);
        }
    }
    __syncthreads();

    // ---- out-proj: out = O @ wout^T + b; store to SCRAMBLED window + roll ----
    {
        short8 afr[4][8];
        #pragma unroll
        for (int mt = 0; mt < 4; ++mt)
            #pragma unroll
            for (int kk = 0; kk < 8; ++kk)
                afr[mt][kk] = *(const short8*)(s_q + (mt * 16 + l16) * QS2 + kk * 32 + quad * 8);

        #pragma unroll
        for (int nt = 0; nt < 2; ++nt) {
            const int N0 = wid * 32 + nt * 16;
            short8 bfr[8];
            const unsigned short* brow = wout_bf + (N0 + l16) * 256 + quad * 8;
            #pragma unroll
            for (int kk = 0; kk < 8; ++kk) bfr[kk] = *(const short8*)(brow + kk * 32);

            f32x4 z = {0.f, 0.f, 0.f, 0.f};
            f32x4 acc[4] = {z, z, z, z};
            #pragma unroll
            for (int kk = 0; kk < 8; ++kk)
                #pragma unroll
                for (int mt = 0; mt < 4; ++mt)
                    acc[mt] = __builtin_amdgcn_mfma_f32_16x16x32_bf16(afr[mt][kk], bfr[kk], acc[mt], 0, 0, 0);

            const float bias = bout[N0 + l16];
            #pragma unroll
            for (int mt = 0; mt < 4; ++mt)
                #pragma unroll
                for (int r = 0; r < 4; ++r) {
                    const int p = mt * 16 + quad * 4 + r;
                    const int ty = p >> 3, tx = p & 7;
                    const int yd = (wyo * 8 + ty + 4) & 255;
                    const int xd = (wxo * 8 + tx + 4) & 255;
                    out[(((size_t)bo * 256 + yd) * 256 + xd) * 256 + N0 + l16] = acc[mt][r] + bias;
                }
        }
    }
}

extern "C" void kernel_launch(void* const* d_in, const int* in_sizes, int n_in,
                              void* d_out, int out_size, void* d_ws, size_t ws_size,
                              hipStream_t stream) {
    const float* x      = (const float*)d_in[0];
    const float* wqkv   = (const float*)d_in[1];
    const float* bqkv   = (const float*)d_in[2];
    const float* relpos = (const float*)d_in[3];
    const float* wout   = (const float*)d_in[4];
    const float* bout   = (const float*)d_in[5];
    float* out = (float*)d_out;

    unsigned short* wqkv_bf = (unsigned short*)d_ws;                      // 393216 B
    unsigned short* wout_bf = (unsigned short*)((char*)d_ws + 393216);    // 131072 B
    float*          relT    = (float*)((char*)d_ws + 524288);             // 131072 B

    prep_kernel<<<768, 256, 0, stream>>>(wqkv, wout, relpos, wqkv_bf, wout_bf, relT);

    hipFuncSetAttribute(reinterpret_cast<const void*>(wmsa_kernel),
                        hipFuncAttributeMaxDynamicSharedMemorySize, LDS_BYTES);

    wmsa_kernel<<<4096, 512, LDS_BYTES, stream>>>(x, wqkv_bf, bqkv, relT, wout_bf, bout, out);
}